// Round 4
// baseline (443.752 us; speedup 1.0000x reference)
//
#include <hip/hip_runtime.h>

// Problem constants (from reference setup_inputs)
#define RES      64
#define NFRAMES  16
#define NB       256      // buckets = flat_bidx = b*16+f; each bucket = 1 MiB grid slab
#define CAP      16384    // slots/bucket; mean 8192, sigma~90 -> 90-sigma headroom
#define CSTRIDE  16       // cursor stride in u32 (64 B: one cache line per counter)
#define IPT      8        // items/thread, bin pass
#define GIPT     8        // items/thread, gather pass

__device__ __forceinline__ unsigned int flat_off(
    float px, float py, float pz, float t, int b, const float* skeys)
{
    int gx = min(max((int)floorf((px * 0.5f + 0.5f) * (float)RES), 0), RES - 1);
    int gy = min(max((int)floorf((py * 0.5f + 0.5f) * (float)RES), 0), RES - 1);
    int gz = min(max((int)floorf((pz * 0.5f + 0.5f) * (float)RES), 0), RES - 1);
    // searchsorted(side='left') == count of keys strictly < t
    int i = 0;
    #pragma unroll
    for (int j = 0; j < NFRAMES; ++j) i += (skeys[j] < t) ? 1 : 0;
    i = min(max(i, 1), NFRAMES - 1);
    float l = skeys[i - 1], r = skeys[i];
    int f = (t - l <= r - t) ? (i - 1) : i;
    return ((unsigned int)(b * NFRAMES + f) << 18)
         | ((unsigned int)gx << 12) | ((unsigned int)gy << 6) | (unsigned int)gz;
}

__global__ __launch_bounds__(256) void zero_cursors(unsigned int* cursors) {
    cursors[threadIdx.x * CSTRIDE] = 0u;
}

// Pass 1: compute flat offset, bin (off, orig_idx) records into 256 buckets.
// Block-level LDS aggregation: 2048 LDS atomics + <=256 global atomics per block.
__global__ __launch_bounds__(256) void bin_kernel(
    const float* __restrict__ pts, const int* __restrict__ bidx,
    const float* __restrict__ ts, const float* __restrict__ keys,
    unsigned int* __restrict__ cursors, uint2* __restrict__ rec, int n)
{
    __shared__ float skeys[NFRAMES];
    __shared__ unsigned int lcnt[NB];
    __shared__ unsigned int lbase[NB];
    const int tid = threadIdx.x;
    if (tid < NFRAMES) skeys[tid] = keys[tid];
    lcnt[tid] = 0u;
    __syncthreads();

    const int base = blockIdx.x * (256 * IPT);
    unsigned int off[IPT], rnk[IPT], bk[IPT];
    bool ok[IPT];
    #pragma unroll
    for (int k = 0; k < IPT; ++k) {
        int i = base + k * 256 + tid;
        ok[k] = i < n;
        if (ok[k]) {
            float px = pts[i * 3 + 0], py = pts[i * 3 + 1], pz = pts[i * 3 + 2];
            off[k] = flat_off(px, py, pz, ts[i], bidx[i], skeys);
            bk[k]  = off[k] >> 18;
            rnk[k] = atomicAdd(&lcnt[bk[k]], 1u);   // local rank within block
        }
    }
    __syncthreads();
    unsigned int c = lcnt[tid];
    lbase[tid] = c ? atomicAdd(&cursors[tid * CSTRIDE], c) : 0u;  // reserve range
    __syncthreads();
    #pragma unroll
    for (int k = 0; k < IPT; ++k) {
        if (ok[k]) {
            unsigned int p = lbase[bk[k]] + rnk[k];
            if (p < CAP)  // statistically unreachable guard
                rec[bk[k] * CAP + p] = make_uint2(off[k], (unsigned int)(base + k * 256 + tid));
        }
    }
}

// Pass 2: per-bucket gather. All gathers of one bucket hit a contiguous 1 MiB
// grid slab -> DRAM row locality + L2 residency for repeats.
__global__ __launch_bounds__(256) void gather_kernel(
    const unsigned int* __restrict__ cursors, const uint2* __restrict__ rec,
    const float* __restrict__ occ, float* __restrict__ out)
{
    const int b     = blockIdx.x >> 3;   // 8 chunk-blocks per bucket (8*2048 = CAP)
    const int chunk = blockIdx.x & 7;
    unsigned int cnt = min(cursors[b * CSTRIDE], (unsigned int)CAP);
    const int j0 = chunk * (256 * GIPT);
    if ((unsigned int)j0 >= cnt) return;

    uint2 r[GIPT]; bool ok[GIPT];
    #pragma unroll
    for (int k = 0; k < GIPT; ++k) {
        int j = j0 + k * 256 + threadIdx.x;
        ok[k] = (unsigned int)j < cnt;
        if (ok[k]) r[k] = rec[b * CAP + j];
    }
    float v[GIPT];
    #pragma unroll
    for (int k = 0; k < GIPT; ++k) if (ok[k]) v[k] = occ[r[k].x];
    #pragma unroll
    for (int k = 0; k < GIPT; ++k) if (ok[k]) out[r[k].y] = v[k];
}

// Fallback: round-2 direct kernel (used only if ws too small)
__global__ __launch_bounds__(256) void direct_kernel(
    const float* __restrict__ pts, const int* __restrict__ bidx,
    const float* __restrict__ ts, const float* __restrict__ occ,
    const float* __restrict__ keys, float* __restrict__ out, int n)
{
    __shared__ float skeys[NFRAMES];
    if (threadIdx.x < NFRAMES) skeys[threadIdx.x] = keys[threadIdx.x];
    __syncthreads();
    const int tid = blockIdx.x * blockDim.x + threadIdx.x;
    const int stride = gridDim.x * blockDim.x;
    for (int i = tid; i < n; i += stride) {
        out[i] = occ[flat_off(pts[i*3], pts[i*3+1], pts[i*3+2], ts[i], bidx[i], skeys)];
    }
}

extern "C" void kernel_launch(void* const* d_in, const int* in_sizes, int n_in,
                              void* d_out, int out_size, void* d_ws, size_t ws_size,
                              hipStream_t stream) {
    const float* pts  = (const float*)d_in[0];
    const int*   bidx = (const int*)  d_in[1];
    const float* ts   = (const float*)d_in[2];
    const float* occ  = (const float*)d_in[3];
    const float* keys = (const float*)d_in[4];
    float* out = (float*)d_out;
    int n = in_sizes[2];  // NUM_PTS

    const size_t curs_bytes = (size_t)NB * CSTRIDE * sizeof(unsigned int);  // 16 KB
    const size_t rec_bytes  = (size_t)NB * CAP * sizeof(uint2);             // 32 MB
    if (ws_size >= curs_bytes + rec_bytes) {
        unsigned int* cursors = (unsigned int*)d_ws;
        uint2* rec = (uint2*)((char*)d_ws + curs_bytes);
        zero_cursors<<<1, 256, 0, stream>>>(cursors);
        int bin_blocks = (n + 256 * IPT - 1) / (256 * IPT);
        bin_kernel<<<bin_blocks, 256, 0, stream>>>(pts, bidx, ts, keys, cursors, rec, n);
        gather_kernel<<<NB * 8, 256, 0, stream>>>(cursors, rec, occ, out);
    } else {
        direct_kernel<<<2048, 256, 0, stream>>>(pts, bidx, ts, occ, keys, out, n);
    }
}

// Round 5
// 369.797 us; speedup vs baseline: 1.2000x; 1.2000x over previous
//
#include <hip/hip_runtime.h>

// Problem constants (from reference setup_inputs)
#define RES      64
#define NFRAMES  16
#define PPT      4      // points per thread (independent gathers in flight)
#define BLOCKS   2048
#define TPB      256

// inputs (d_in order): pts(N,3) f32, bidx(N) i32, ts(N) f32,
//                      occ_grid(256,64,64,64) f32, ts_keyframes(16) f32, num_frames(1) i32
// output: (N,) f32

template<bool EXACT>
__global__ __launch_bounds__(TPB) void occ_gather_kernel(
    const float* __restrict__ pts,
    const int*   __restrict__ bidx,
    const float* __restrict__ ts,
    const float* __restrict__ occ,
    const float* __restrict__ keys,
    float*       __restrict__ out,
    int n)
{
    // keys pointer + unrolled constant index -> compiler emits scalar s_loads;
    // no LDS, no __syncthreads.
    float kk[NFRAMES];
    #pragma unroll
    for (int j = 0; j < NFRAMES; ++j) kk[j] = keys[j];

    const int tid    = blockIdx.x * blockDim.x + threadIdx.x;
    const int stride = gridDim.x * blockDim.x;

    int   idxv[PPT];
    float pxv[PPT], pyv[PPT], pzv[PPT], tv[PPT];
    int   bv[PPT];
    bool  ok[PPT];

    // 1) streaming loads — nontemporal (single-use; keep L2 for gather lines)
    #pragma unroll
    for (int k = 0; k < PPT; ++k) {
        int idx = tid + k * stride;
        idxv[k] = idx;
        ok[k] = EXACT ? true : (idx < n);
        if (ok[k]) {
            pxv[k] = __builtin_nontemporal_load(&pts[idx * 3 + 0]);
            pyv[k] = __builtin_nontemporal_load(&pts[idx * 3 + 1]);
            pzv[k] = __builtin_nontemporal_load(&pts[idx * 3 + 2]);
            tv[k]  = __builtin_nontemporal_load(&ts[idx]);
            bv[k]  = __builtin_nontemporal_load(&bidx[idx]);
        }
    }

    // 2) compute flat offsets for all PPT points (no memory deps between them)
    unsigned int off[PPT];
    #pragma unroll
    for (int k = 0; k < PPT; ++k) {
        if (!ok[k]) continue;
        int gx = min(max((int)floorf((pxv[k] * 0.5f + 0.5f) * (float)RES), 0), RES - 1);
        int gy = min(max((int)floorf((pyv[k] * 0.5f + 0.5f) * (float)RES), 0), RES - 1);
        int gz = min(max((int)floorf((pzv[k] * 0.5f + 0.5f) * (float)RES), 0), RES - 1);

        // searchsorted(side='left') == count of keys strictly < t
        int i = 0;
        #pragma unroll
        for (int j = 0; j < NFRAMES; ++j) i += (kk[j] < tv[k]) ? 1 : 0;
        i = min(max(i, 1), NFRAMES - 1);
        float l = kk[i - 1];
        float r = kk[i];
        int f = (tv[k] - l <= r - tv[k]) ? (i - 1) : i;

        off[k] = ((unsigned int)(bv[k] * NFRAMES + f) << 18)
               | ((unsigned int)gx << 12)
               | ((unsigned int)gy << 6)
               |  (unsigned int)gz;
    }

    // 3) gathers (PPT independent loads in flight per thread; cached — 21% of
    //    draws are line-repeats) then nontemporal stores
    float val[PPT];
    #pragma unroll
    for (int k = 0; k < PPT; ++k) {
        if (ok[k]) val[k] = occ[off[k]];
    }
    #pragma unroll
    for (int k = 0; k < PPT; ++k) {
        if (ok[k]) __builtin_nontemporal_store(val[k], &out[idxv[k]]);
    }
}

extern "C" void kernel_launch(void* const* d_in, const int* in_sizes, int n_in,
                              void* d_out, int out_size, void* d_ws, size_t ws_size,
                              hipStream_t stream) {
    const float* pts  = (const float*)d_in[0];
    const int*   bidx = (const int*)  d_in[1];
    const float* ts   = (const float*)d_in[2];
    const float* occ  = (const float*)d_in[3];
    const float* keys = (const float*)d_in[4];
    float* out = (float*)d_out;

    int n = in_sizes[2];  // NUM_PTS
    if (n == BLOCKS * TPB * PPT) {
        // exact cover: no bounds checks at all
        occ_gather_kernel<true><<<BLOCKS, TPB, 0, stream>>>(pts, bidx, ts, occ, keys, out, n);
    } else {
        int blocks = (n + TPB * PPT - 1) / (TPB * PPT);
        occ_gather_kernel<false><<<blocks, TPB, 0, stream>>>(pts, bidx, ts, occ, keys, out, n);
    }
}